// Round 4
// baseline (11469.873 us; speedup 1.0000x reference)
//
#include <hip/hip_runtime.h>

// Problem constants (B=16, N=M=1024, D=32)
constexpr int   NN       = 1024;
constexpr float EPSf     = 1e-3f;
constexpr int   MAX_ITER = 100;

// exp2-domain scale: x = (v - C) * (1/eps) * log2(e)
#define K2      1442.6950408889634f
#define LN2f    0.6931471805599453f
#define INV_LN2 1.4426950408889634f
#define INV_EPS 1000.0f
#define LOGK    (-6.9314616f)   // log(1/1024 + 1e-8)

// hardware transcendentals (avoid libm name collisions)
#define EXP2F(x) __builtin_amdgcn_exp2f(x)   // 2^x
#define LOG2F(x) __builtin_amdgcn_logf(x)    // log2(x)

typedef _Float16 half8 __attribute__((ext_vector_type(8)));

// ---------------------------------------------------------------------------
// LLC-coherent access helpers. sc0 sc1 bits make the single access bypass the
// (non-cross-XCD-coherent) L1/L2 — NO cache-wide invalidation is emitted,
// unlike fences/acquire ops (round-1 lesson: those cost 3.4 GB of C refetch).
// waitcnt folded into the load asm so the compiler can't hoist consumers.
// ---------------------------------------------------------------------------
__device__ __forceinline__ float4 ldg_cohere_f4(const float* p) {
    float4 r;
    asm volatile("global_load_dwordx4 %0, %1, off sc0 sc1\n\ts_waitcnt vmcnt(0)"
                 : "=v"(r) : "v"(p) : "memory");
    return r;
}
__device__ __forceinline__ void stg_cohere_f32(float* p, float x) {
    asm volatile("global_store_dword %0, %1, off sc0 sc1" :: "v"(p), "v"(x) : "memory");
}

// ---------------------------------------------------------------------------
// dist[b][p][q] = sum_d (A[b][p][d] - Bm[b][q][d])^2, stored fp16. (unchanged)
// ---------------------------------------------------------------------------
__global__ __launch_bounds__(256) void build_dist(
    const float* __restrict__ A, const float* __restrict__ Bm,
    _Float16* __restrict__ out)
{
    __shared__ float aLds[16 * 32];
    __shared__ float bLds[256 * 33];
    const int b  = blockIdx.x >> 6;       // 16 * 64 blocks
    const int pt = blockIdx.x & 63;
    const int t  = threadIdx.x;

    const float* Ab = A  + ((size_t)b * NN + pt * 16) * 32;
    const float* Bb = Bm + (size_t)b * NN * 32;

    if (t < 128) ((float4*)aLds)[t] = ((const float4*)Ab)[t];

    for (int qt = 0; qt < 4; ++qt) {
        __syncthreads();
        const float4* src = (const float4*)(Bb + qt * 256 * 32);
#pragma unroll
        for (int i = 0; i < 8; ++i) {
            int j = t + (i << 8);
            float4 val = src[j];
            int q = j >> 3, dd = (j & 7) << 2;
            float* dst = &bLds[q * 33 + dd];
            dst[0] = val.x; dst[1] = val.y; dst[2] = val.z; dst[3] = val.w;
        }
        __syncthreads();

        float br[32];
#pragma unroll
        for (int d = 0; d < 32; ++d) br[d] = bLds[t * 33 + d];

#pragma unroll
        for (int p = 0; p < 16; ++p) {
            float acc = 0.f;
#pragma unroll
            for (int d4 = 0; d4 < 8; ++d4) {
                float4 a4 = ((const float4*)(aLds + p * 32))[d4];
                float dx = a4.x - br[d4 * 4 + 0];
                float dy = a4.y - br[d4 * 4 + 1];
                float dz = a4.z - br[d4 * 4 + 2];
                float dw = a4.w - br[d4 * 4 + 3];
                acc += dx * dx + dy * dy + dz * dz + dw * dw;
            }
            out[((size_t)b * NN + pt * 16 + p) * NN + qt * 256 + t] = (_Float16)acc;
        }
    }
}

// ---------------------------------------------------------------------------
// One 2-row LSE half-step (bit-identical math to the verified baseline pass:
// fast prev-shifted exp2 path + classic max-shifted fallback). uo0/uo1 are
// the carried previous values (wave-uniform registers, replacing the memory
// re-read). Stores the new values LLC-coherently; returns |du| contribution
// (wave-uniform).
// ---------------------------------------------------------------------------
__device__ __forceinline__ float pair_step(
    const _Float16* __restrict__ Cb, const float4* __restrict__ V4,
    float* __restrict__ outb, int r, int lane, float& uo0, float& uo1)
{
    const half8* r0 = (const half8*)(Cb + (size_t)r * NN);
    const half8* r1 = (const half8*)(Cb + (size_t)(r + 1) * NN);

    const float M0 = (LOGK - uo0 * INV_EPS) * INV_LN2;
    const float M1 = (LOGK - uo1 * INV_EPS) * INV_LN2;

    float x0[16], x1[16];
#pragma unroll
    for (int k = 0; k < 2; ++k) {
        const int m_ = lane + (k << 6);
        half8 c0 = r0[m_];
        half8 c1 = r1[m_];
        float4 va = V4[2 * m_], vb = V4[2 * m_ + 1];
        float vv[8] = {va.x, va.y, va.z, va.w, vb.x, vb.y, vb.z, vb.w};
#pragma unroll
        for (int j = 0; j < 8; ++j) {
            x0[8 * k + j] = fmaf((float)c0[j], -K2, vv[j]);
            x1[8 * k + j] = fmaf((float)c1[j], -K2, vv[j]);
        }
    }
    float s0 = 0.f, s1 = 0.f;
#pragma unroll
    for (int i = 0; i < 16; ++i) {
        s0 += EXP2F(x0[i] - M0);
        s1 += EXP2F(x1[i] - M1);
    }
#pragma unroll
    for (int off = 32; off > 0; off >>= 1) {
        s0 += __shfl_xor(s0, off);
        s1 += __shfl_xor(s1, off);
    }

    float lse2_0, lse2_1;
    if (__builtin_expect(!(s0 >= 1e-27f && s0 <= 1e38f) ||
                         !(s1 >= 1e-27f && s1 <= 1e38f), 0)) {
        // fallback: classic max-shifted LSE (fires at it=0 and on drift)
        float m0 = x0[0], m1 = x1[0];
#pragma unroll
        for (int i = 1; i < 16; ++i) { m0 = fmaxf(m0, x0[i]); m1 = fmaxf(m1, x1[i]); }
#pragma unroll
        for (int off = 32; off > 0; off >>= 1) {
            m0 = fmaxf(m0, __shfl_xor(m0, off));
            m1 = fmaxf(m1, __shfl_xor(m1, off));
        }
        float t0 = 0.f, t1 = 0.f;
#pragma unroll
        for (int i = 0; i < 16; ++i) { t0 += EXP2F(x0[i] - m0); t1 += EXP2F(x1[i] - m1); }
#pragma unroll
        for (int off = 32; off > 0; off >>= 1) {
            t0 += __shfl_xor(t0, off);
            t1 += __shfl_xor(t1, off);
        }
        lse2_0 = m0 + LOG2F(t0);
        lse2_1 = m1 + LOG2F(t1);
    } else {
        lse2_0 = M0 + LOG2F(s0);
        lse2_1 = M1 + LOG2F(s1);
    }

    const float n0 = EPSf * (LOGK - lse2_0 * LN2f);
    const float n1 = EPSf * (LOGK - lse2_1 * LN2f);
    const float werr = fabsf(n0 - uo0) + fabsf(n1 - uo1);
    if (lane == 0) {
        stg_cohere_f32(outb + r,     n0);
        stg_cohere_f32(outb + r + 1, n1);
    }
    uo0 = n0; uo1 = n1;
    return werr;
}

// ---------------------------------------------------------------------------
// Sense-reversing per-batch barrier (64 blocks). RELAXED spin (no per-poll
// cache invalidation!), one RELEASE RMW to arrive (orders this block's prior
// coherent stores at the LLC). No fences anywhere.
// ---------------------------------------------------------------------------
__device__ __forceinline__ void batch_bar(int* cnt, int* gen, int tid)
{
    __syncthreads();
    if (tid == 0) {
        int g = __hip_atomic_load(gen, __ATOMIC_RELAXED, __HIP_MEMORY_SCOPE_AGENT);
        int a = __hip_atomic_fetch_add(cnt, 1, __ATOMIC_RELEASE, __HIP_MEMORY_SCOPE_AGENT);
        if (a == 63) {
            __hip_atomic_store(cnt, 0, __ATOMIC_RELAXED, __HIP_MEMORY_SCOPE_AGENT);
            __hip_atomic_fetch_add(gen, 1, __ATOMIC_RELEASE, __HIP_MEMORY_SCOPE_AGENT);
        } else {
            while (__hip_atomic_load(gen, __ATOMIC_RELAXED, __HIP_MEMORY_SCOPE_AGENT) == g)
                __builtin_amdgcn_s_sleep(1);
        }
    }
    __syncthreads();
}

// ---------------------------------------------------------------------------
// Persistent Sinkhorn: all 100 iterations in one launch, zero fences.
// Grid 1024 x 256, __launch_bounds__(256,4): 4 blocks/CU co-resident
// (empirically proven by round-1's completion at identical config).
// Mapping: xcd = blk&7 (round-robin XCD heuristic), batch = xcd + 8*(slot>=64)
// so a batch's 64 blocks cluster on one XCD (L2 locality for its C slab);
// correctness does NOT depend on this mapping (all shared-mutable data is
// LLC-coherent). Block owns 16 rows: 4/wave as two sequential pairs.
// C/CT are read-only during the loop -> normal cached loads, stay L2/LLC-hot.
// ---------------------------------------------------------------------------
__global__ __launch_bounds__(256, 4) void sinkhorn_persist(
    const _Float16* __restrict__ C, const _Float16* __restrict__ CT,
    float* __restrict__ u, float* __restrict__ v,
    float* __restrict__ errB,   // [MAX_ITER][16] per-batch sum|du|
    float* __restrict__ gerr,   // [MAX_ITER] global err
    int* __restrict__ gdone,    // [MAX_ITER] batch-completion count
    int* __restrict__ bar)      // [16][2] (cnt, gen)
{
    __shared__ float ldsvk[1024];
    __shared__ float red[4];
    __shared__ int s_flag;
    const int tid = threadIdx.x, wave = tid >> 6, lane = tid & 63;
    const int xcd = blockIdx.x & 7, slot = blockIdx.x >> 3;
    const int b = xcd + ((slot >= 64) ? 8 : 0);
    const int l = slot & 63;

    const _Float16* Cb  = C  + ((size_t)b << 20);
    const _Float16* CTb = CT + ((size_t)b << 20);
    float* ub = u + (b << 10);
    float* vb = v + (b << 10);
    int* cntp = bar + (b << 1);
    int* genp = bar + (b << 1) + 1;
    const float4* V4 = (const float4*)ldsvk;

    const int rbase = (l << 4) + (wave << 1);   // rows rbase,rbase+1, +8,+9
    float cu0 = 0.f, cu1 = 0.f, cu2 = 0.f, cu3 = 0.f;   // carried u rows
    float cv0 = 0.f, cv1 = 0.f, cv2 = 0.f, cv3 = 0.f;   // carried v rows

    for (int it = 0; it < MAX_ITER; ++it) {
        // ---------------- U phase: u <- f(C, v) ----------------
        {   float4 t = ldg_cohere_f4(vb + (tid << 2));
            t.x *= K2; t.y *= K2; t.z *= K2; t.w *= K2;
            ((float4*)ldsvk)[tid] = t;
        }
        __syncthreads();
        float w0 = pair_step(Cb, V4, ub, rbase,     lane, cu0, cu1);
        float w1 = pair_step(Cb, V4, ub, rbase + 8, lane, cu2, cu3);
        if (lane == 0) red[wave] = w0 + w1;
        __syncthreads();
        if (tid == 0)
            atomicAdd(errB + (it << 4) + b, red[0] + red[1] + red[2] + red[3]);
        asm volatile("s_waitcnt vmcnt(0)" ::: "memory");
        batch_bar(cntp, genp, tid);              // u[b] complete at LLC

        if (l == 0 && tid == 0) {                // publish batch err, once
            float e = __hip_atomic_load(errB + (it << 4) + b,
                                        __ATOMIC_RELAXED, __HIP_MEMORY_SCOPE_AGENT);
            atomicAdd(gerr + it, e);
            __hip_atomic_fetch_add(gdone + it, 1,
                                   __ATOMIC_RELEASE, __HIP_MEMORY_SCOPE_AGENT);
        }

        // ---------------- V phase: v <- f(CT, u) ----------------
        {   float4 t = ldg_cohere_f4(ub + (tid << 2));
            t.x *= K2; t.y *= K2; t.z *= K2; t.w *= K2;
            ((float4*)ldsvk)[tid] = t;
        }
        __syncthreads();
        pair_step(CTb, V4, vb, rbase,     lane, cv0, cv1);
        pair_step(CTb, V4, vb, rbase + 8, lane, cv2, cv3);
        asm volatile("s_waitcnt vmcnt(0)" ::: "memory");
        batch_bar(cntp, genp, tid);              // v[b] complete at LLC

        // ---- freeze chain (same semantics as baseline dflag chain) ----
        if (tid == 0) {
            while (__hip_atomic_load(gdone + it, __ATOMIC_RELAXED,
                                     __HIP_MEMORY_SCOPE_AGENT) < 16)
                __builtin_amdgcn_s_sleep(2);
            float e = __hip_atomic_load(gerr + it, __ATOMIC_RELAXED,
                                        __HIP_MEMORY_SCOPE_AGENT);
            s_flag = (e < 1.6f) ? 1 : 0;
        }
        __syncthreads();
        if (s_flag) break;   // frozen: u,v keep their converged values
    }
}

// ---------------------------------------------------------------------------
// cost = mean_b sum_ij exp((u_i + v_j - C_ij)/eps) * C_ij   (unchanged)
// ---------------------------------------------------------------------------
__global__ __launch_bounds__(256) void cost_kernel(
    const _Float16* __restrict__ C, const float* __restrict__ u,
    const float* __restrict__ v, float* __restrict__ out)
{
    __shared__ float ldsv[1024];
    __shared__ float red[4];
    const int tid = threadIdx.x, wave = tid >> 6, lane = tid & 63;
    const int b = blockIdx.x >> 5, l = blockIdx.x & 31;

    ((float4*)ldsv)[tid] = ((const float4*)(v + (b << 10)))[tid];
    __syncthreads();

    const _Float16* Cb = C + ((size_t)b << 20);
    const float* ub = u + (b << 10);
    const float4* V4 = (const float4*)ldsv;
    float csum = 0.f;
    for (int rr = 0; rr < 8; ++rr) {
        const int row = (l << 5) + (wave << 3) + rr;
        const float ui = ub[row];
        const half8* Crow = (const half8*)(Cb + (size_t)row * NN);
#pragma unroll
        for (int k = 0; k < 2; ++k) {
            const int m = lane + (k << 6);
            half8 c8 = Crow[m];
            float4 va = V4[2 * m];
            float4 vb = V4[2 * m + 1];
            float vv[8] = {va.x, va.y, va.z, va.w, vb.x, vb.y, vb.z, vb.w};
#pragma unroll
            for (int j = 0; j < 8; ++j) {
                float c = (float)c8[j];
                csum += EXP2F((ui + vv[j] - c) * K2) * c;
            }
        }
    }
#pragma unroll
    for (int off = 32; off > 0; off >>= 1) csum += __shfl_xor(csum, off);
    if (lane == 0) red[wave] = csum;
    __syncthreads();
    if (tid == 0)
        atomicAdd(out, (red[0] + red[1] + red[2] + red[3]) * (1.0f / 16.0f));
}

extern "C" void kernel_launch(void* const* d_in, const int* in_sizes, int n_in,
                              void* d_out, int out_size, void* d_ws, size_t ws_size,
                              hipStream_t stream) {
    const float* x = (const float*)d_in[0];  // output: [16,1024,32] fp32
    const float* y = (const float*)d_in[1];  // labels: [16,1024,32] fp32

    char* wsb = (char*)d_ws;
    _Float16* C  = (_Float16*)wsb;                   // 32 MB
    _Float16* CT = (_Float16*)(wsb + 33554432);      // 32 MB
    float* u     = (float*)(wsb + 67108864);         // 16384 floats
    float* v     = u + 16384;                        // 16384 floats
    float* errB  = v + 16384;                        // [100][16]
    float* gerr  = errB + 1600;                      // [100]
    int*   gdone = (int*)(gerr + 100);               // [100]
    int*   bar   = gdone + 100;                      // [16][2]
    float* out   = (float*)d_out;

    // u, v, errB, gerr, gdone, bar contiguous — zero them (+ out) every call
    (void)hipMemsetAsync(u, 0,
        (size_t)(2 * 16384 + 1600 + 100 + 100 + 32) * 4, stream);
    (void)hipMemsetAsync(out, 0, sizeof(float), stream);

    build_dist<<<dim3(16 * 64), dim3(256), 0, stream>>>(x, y, C);
    build_dist<<<dim3(16 * 64), dim3(256), 0, stream>>>(y, x, CT);

    // one persistent launch replaces 200 lse_pass dispatches
    sinkhorn_persist<<<dim3(1024), dim3(256), 0, stream>>>(
        C, CT, u, v, errB, gerr, gdone, bar);

    cost_kernel<<<dim3(512), dim3(256), 0, stream>>>(C, u, v, out);
}

// Round 5
// 6490.700 us; speedup vs baseline: 1.7671x; 1.7671x over previous
//
#include <hip/hip_runtime.h>

// Problem constants (B=16, N=M=1024, D=32)
constexpr int   NN       = 1024;
constexpr float EPSf     = 1e-3f;
constexpr int   MAX_ITER = 100;

// exp2-domain scale: x = (v - C) * (1/eps) * log2(e)
#define K2      1442.6950408889634f
#define LN2f    0.6931471805599453f
#define INV_LN2 1.4426950408889634f
#define INV_EPS 1000.0f
#define LOGK    (-6.9314616f)   // log(1/1024 + 1e-8)

// hardware transcendentals (avoid libm name collisions)
#define EXP2F(x) __builtin_amdgcn_exp2f(x)   // 2^x
#define LOG2F(x) __builtin_amdgcn_logf(x)    // log2(x)

typedef _Float16 half8 __attribute__((ext_vector_type(8)));

// ---------------------------------------------------------------------------
// LLC-coherent single-access helpers (sc0 sc1: bypass non-coherent L1/L2 for
// THIS access only — no cache-wide invalidation, round-1 lesson).
// ---------------------------------------------------------------------------
__device__ __forceinline__ float4 ldg_cohere_f4(const float* p) {
    float4 r;
    asm volatile("global_load_dwordx4 %0, %1, off sc0 sc1\n\ts_waitcnt vmcnt(0)"
                 : "=v"(r) : "v"(p) : "memory");
    return r;
}
__device__ __forceinline__ void stg_cohere_f32(float* p, float x) {
    asm volatile("global_store_dword %0, %1, off sc0 sc1" :: "v"(p), "v"(x) : "memory");
}

// ---------------------------------------------------------------------------
// dist[b][p][q] = sum_d (A[b][p][d] - Bm[b][q][d])^2, stored fp16. (unchanged)
// ---------------------------------------------------------------------------
__global__ __launch_bounds__(256) void build_dist(
    const float* __restrict__ A, const float* __restrict__ Bm,
    _Float16* __restrict__ out)
{
    __shared__ float aLds[16 * 32];
    __shared__ float bLds[256 * 33];
    const int b  = blockIdx.x >> 6;       // 16 * 64 blocks
    const int pt = blockIdx.x & 63;
    const int t  = threadIdx.x;

    const float* Ab = A  + ((size_t)b * NN + pt * 16) * 32;
    const float* Bb = Bm + (size_t)b * NN * 32;

    if (t < 128) ((float4*)aLds)[t] = ((const float4*)Ab)[t];

    for (int qt = 0; qt < 4; ++qt) {
        __syncthreads();
        const float4* src = (const float4*)(Bb + qt * 256 * 32);
#pragma unroll
        for (int i = 0; i < 8; ++i) {
            int j = t + (i << 8);
            float4 val = src[j];
            int q = j >> 3, dd = (j & 7) << 2;
            float* dst = &bLds[q * 33 + dd];
            dst[0] = val.x; dst[1] = val.y; dst[2] = val.z; dst[3] = val.w;
        }
        __syncthreads();

        float br[32];
#pragma unroll
        for (int d = 0; d < 32; ++d) br[d] = bLds[t * 33 + d];

#pragma unroll
        for (int p = 0; p < 16; ++p) {
            float acc = 0.f;
#pragma unroll
            for (int d4 = 0; d4 < 8; ++d4) {
                float4 a4 = ((const float4*)(aLds + p * 32))[d4];
                float dx = a4.x - br[d4 * 4 + 0];
                float dy = a4.y - br[d4 * 4 + 1];
                float dz = a4.z - br[d4 * 4 + 2];
                float dw = a4.w - br[d4 * 4 + 3];
                acc += dx * dx + dy * dy + dz * dz + dw * dw;
            }
            out[((size_t)b * NN + pt * 16 + p) * NN + qt * 256 + t] = (_Float16)acc;
        }
    }
}

// 2-row fragment of C (4 x 16B loads); load separated from compute so the
// caller can issue loads early (cross-barrier / cross-stage prefetch).
struct RowPair { half8 a0, a1, b0, b1; };
__device__ __forceinline__ RowPair load_pair(const _Float16* Cb, int r, int lane)
{
    const half8* r0 = (const half8*)(Cb + (size_t)r * NN);
    const half8* r1 = (const half8*)(Cb + (size_t)(r + 1) * NN);
    RowPair p;
    p.a0 = r0[lane]; p.a1 = r0[lane + 64];
    p.b0 = r1[lane]; p.b1 = r1[lane + 64];
    return p;
}

// ---------------------------------------------------------------------------
// One 2-row LSE half-step on preloaded C data — math bit-identical to the
// verified baseline pass (fast prev-shifted path + max-shifted fallback).
// uo0/uo1 carried in registers (wave-uniform). Coherent stores of results.
// ---------------------------------------------------------------------------
__device__ __forceinline__ float pair_compute(
    const RowPair& P, const float4* __restrict__ V4,
    float* __restrict__ outb, int r, int lane, float& uo0, float& uo1)
{
    const float M0 = (LOGK - uo0 * INV_EPS) * INV_LN2;
    const float M1 = (LOGK - uo1 * INV_EPS) * INV_LN2;

    float x0[16], x1[16];
#pragma unroll
    for (int k = 0; k < 2; ++k) {
        const int m_ = lane + (k << 6);
        const half8 c0 = k ? P.a1 : P.a0;
        const half8 c1 = k ? P.b1 : P.b0;
        float4 va = V4[2 * m_], vb = V4[2 * m_ + 1];
        float vv[8] = {va.x, va.y, va.z, va.w, vb.x, vb.y, vb.z, vb.w};
#pragma unroll
        for (int j = 0; j < 8; ++j) {
            x0[8 * k + j] = fmaf((float)c0[j], -K2, vv[j]);
            x1[8 * k + j] = fmaf((float)c1[j], -K2, vv[j]);
        }
    }
    float s0 = 0.f, s1 = 0.f;
#pragma unroll
    for (int i = 0; i < 16; ++i) {
        s0 += EXP2F(x0[i] - M0);
        s1 += EXP2F(x1[i] - M1);
    }
#pragma unroll
    for (int off = 32; off > 0; off >>= 1) {
        s0 += __shfl_xor(s0, off);
        s1 += __shfl_xor(s1, off);
    }

    float lse2_0, lse2_1;
    if (__builtin_expect(!(s0 >= 1e-27f && s0 <= 1e38f) ||
                         !(s1 >= 1e-27f && s1 <= 1e38f), 0)) {
        // fallback: classic max-shifted LSE (fires at it=0 and on drift)
        float m0 = x0[0], m1 = x1[0];
#pragma unroll
        for (int i = 1; i < 16; ++i) { m0 = fmaxf(m0, x0[i]); m1 = fmaxf(m1, x1[i]); }
#pragma unroll
        for (int off = 32; off > 0; off >>= 1) {
            m0 = fmaxf(m0, __shfl_xor(m0, off));
            m1 = fmaxf(m1, __shfl_xor(m1, off));
        }
        float t0 = 0.f, t1 = 0.f;
#pragma unroll
        for (int i = 0; i < 16; ++i) { t0 += EXP2F(x0[i] - m0); t1 += EXP2F(x1[i] - m1); }
#pragma unroll
        for (int off = 32; off > 0; off >>= 1) {
            t0 += __shfl_xor(t0, off);
            t1 += __shfl_xor(t1, off);
        }
        lse2_0 = m0 + LOG2F(t0);
        lse2_1 = m1 + LOG2F(t1);
    } else {
        lse2_0 = M0 + LOG2F(s0);
        lse2_1 = M1 + LOG2F(s1);
    }

    const float n0 = EPSf * (LOGK - lse2_0 * LN2f);
    const float n1 = EPSf * (LOGK - lse2_1 * LN2f);
    const float werr = fabsf(n0 - uo0) + fabsf(n1 - uo1);
    if (lane == 0) {
        stg_cohere_f32(outb + r,     n0);
        stg_cohere_f32(outb + r + 1, n1);
    }
    uo0 = n0; uo1 = n1;
    return werr;
}

// ---------------------------------------------------------------------------
// Sense-reversing per-batch barrier. cnt and gen each own a PRIVATE 256 B
// line (the round-1/4 killer was all 16 batches' words sharing ONE line —
// every RMW contended with every poll device-wide). Relaxed spin, one
// release RMW to arrive. No fences.
// ---------------------------------------------------------------------------
__device__ __forceinline__ void batch_bar(int* cnt, int* gen, int tid)
{
    __syncthreads();
    if (tid == 0) {
        int g = __hip_atomic_load(gen, __ATOMIC_RELAXED, __HIP_MEMORY_SCOPE_AGENT);
        int a = __hip_atomic_fetch_add(cnt, 1, __ATOMIC_RELEASE, __HIP_MEMORY_SCOPE_AGENT);
        if (a == 63) {
            __hip_atomic_store(cnt, 0, __ATOMIC_RELAXED, __HIP_MEMORY_SCOPE_AGENT);
            __hip_atomic_fetch_add(gen, 1, __ATOMIC_RELEASE, __HIP_MEMORY_SCOPE_AGENT);
        } else {
            while (__hip_atomic_load(gen, __ATOMIC_RELAXED, __HIP_MEMORY_SCOPE_AGENT) == g)
                __builtin_amdgcn_s_sleep(4);
        }
    }
    __syncthreads();
}

// ---------------------------------------------------------------------------
// Persistent Sinkhorn, contention-fixed:
//  - every sync word on its own 256B line (barcnt/bargen/gdone/gerr/errB)
//  - freeze flag replicated 8x (per blk&7), one writer block -> <=128
//    pollers per line instead of 1024
//  - C/CT row prefetch issued BEFORE each barrier (latency hides under wait)
// Grid 1024 x 256, __launch_bounds__(256,4): co-residency proven in r1/r4.
// ---------------------------------------------------------------------------
__global__ __launch_bounds__(256, 4) void sinkhorn_persist(
    const _Float16* __restrict__ C, const _Float16* __restrict__ CT,
    float* __restrict__ u, float* __restrict__ v,
    float* __restrict__ errB,    // [100][16] x 16-float lines
    float* __restrict__ gerr,    // [100] x 64-float lines
    int* __restrict__ gdone,     // [100] x 64-int lines
    int* __restrict__ barcnt,    // [16] x 64-int lines
    int* __restrict__ bargen,    // [16] x 64-int lines
    int* __restrict__ flagrep)   // [100][8] x 64-int lines
{
    __shared__ float ldsvk[1024];
    __shared__ float red[4];
    __shared__ int s_flag;
    const int tid = threadIdx.x, wave = tid >> 6, lane = tid & 63;
    const int xcd = blockIdx.x & 7, slot = blockIdx.x >> 3;
    const int b = xcd + ((slot >= 64) ? 8 : 0);
    const int l = slot & 63;

    const _Float16* Cb  = C  + ((size_t)b << 20);
    const _Float16* CTb = CT + ((size_t)b << 20);
    float* ub = u + (b << 10);
    float* vb = v + (b << 10);
    int* cntp = barcnt + (b << 6);
    int* genp = bargen + (b << 6);
    const float4* V4 = (const float4*)ldsvk;

    const int rbase = (l << 4) + (wave << 1);   // rows rbase,+1 and rbase+8,+9
    float cu0 = 0.f, cu1 = 0.f, cu2 = 0.f, cu3 = 0.f;
    float cv0 = 0.f, cv1 = 0.f, cv2 = 0.f, cv3 = 0.f;

    RowPair p1 = load_pair(Cb, rbase, lane);    // prologue prefetch (u pair-1)

    for (int it = 0; it < MAX_ITER; ++it) {
        // ---------------- U phase: u <- f(C, v) ----------------
        {   float4 t = ldg_cohere_f4(vb + (tid << 2));
            t.x *= K2; t.y *= K2; t.z *= K2; t.w *= K2;
            ((float4*)ldsvk)[tid] = t;
        }
        RowPair p2 = load_pair(Cb, rbase + 8, lane);   // pair-2 under stage+sync
        __syncthreads();
        float w0 = pair_compute(p1, V4, ub, rbase,     lane, cu0, cu1);
        float w1 = pair_compute(p2, V4, ub, rbase + 8, lane, cu2, cu3);
        p1 = load_pair(CTb, rbase, lane);              // v pair-1 under barrier
        if (lane == 0) red[wave] = w0 + w1;
        __syncthreads();
        if (tid == 0)
            atomicAdd(errB + ((it << 4) + b) * 16, red[0] + red[1] + red[2] + red[3]);
        batch_bar(cntp, genp, tid);                    // u[b] complete at LLC

        if (l == 0 && tid == 0) {                      // publish batch err, once
            float e = __hip_atomic_load(errB + ((it << 4) + b) * 16,
                                        __ATOMIC_RELAXED, __HIP_MEMORY_SCOPE_AGENT);
            atomicAdd(gerr + (it << 6), e);
            __hip_atomic_fetch_add(gdone + (it << 6), 1,
                                   __ATOMIC_RELEASE, __HIP_MEMORY_SCOPE_AGENT);
        }

        // ---------------- V phase: v <- f(CT, u) ----------------
        {   float4 t = ldg_cohere_f4(ub + (tid << 2));
            t.x *= K2; t.y *= K2; t.z *= K2; t.w *= K2;
            ((float4*)ldsvk)[tid] = t;
        }
        RowPair q2 = load_pair(CTb, rbase + 8, lane);  // pair-2 under stage+sync
        __syncthreads();
        pair_compute(p1, V4, vb, rbase,     lane, cv0, cv1);
        pair_compute(q2, V4, vb, rbase + 8, lane, cv2, cv3);
        p1 = load_pair(Cb, rbase, lane);               // next-iter u pair-1 under barrier
        batch_bar(cntp, genp, tid);                    // v[b] complete at LLC

        // ---- freeze chain: writer computes flag, 8 padded replicas ----
        if (blockIdx.x == 0 && tid == 0) {
            while (__hip_atomic_load(gdone + (it << 6), __ATOMIC_RELAXED,
                                     __HIP_MEMORY_SCOPE_AGENT) < 16)
                __builtin_amdgcn_s_sleep(8);
            float e = __hip_atomic_load(gerr + (it << 6), __ATOMIC_RELAXED,
                                        __HIP_MEMORY_SCOPE_AGENT);
            const int f = (e < 1.6f) ? 2 : 1;          // 0 = not ready
#pragma unroll
            for (int x = 0; x < 8; ++x)
                __hip_atomic_store(flagrep + ((it << 3) + x) * 64, f,
                                   __ATOMIC_RELAXED, __HIP_MEMORY_SCOPE_AGENT);
        }
        if (tid == 0) {
            int f;
            while ((f = __hip_atomic_load(flagrep + ((it << 3) + xcd) * 64,
                                          __ATOMIC_RELAXED, __HIP_MEMORY_SCOPE_AGENT)) == 0)
                __builtin_amdgcn_s_sleep(4);
            s_flag = f - 1;
        }
        __syncthreads();
        if (s_flag) break;   // frozen: u,v keep their converged values
    }
}

// ---------------------------------------------------------------------------
// cost = mean_b sum_ij exp((u_i + v_j - C_ij)/eps) * C_ij   (unchanged)
// ---------------------------------------------------------------------------
__global__ __launch_bounds__(256) void cost_kernel(
    const _Float16* __restrict__ C, const float* __restrict__ u,
    const float* __restrict__ v, float* __restrict__ out)
{
    __shared__ float ldsv[1024];
    __shared__ float red[4];
    const int tid = threadIdx.x, wave = tid >> 6, lane = tid & 63;
    const int b = blockIdx.x >> 5, l = blockIdx.x & 31;

    ((float4*)ldsv)[tid] = ((const float4*)(v + (b << 10)))[tid];
    __syncthreads();

    const _Float16* Cb = C + ((size_t)b << 20);
    const float* ub = u + (b << 10);
    const float4* V4 = (const float4*)ldsv;
    float csum = 0.f;
    for (int rr = 0; rr < 8; ++rr) {
        const int row = (l << 5) + (wave << 3) + rr;
        const float ui = ub[row];
        const half8* Crow = (const half8*)(Cb + (size_t)row * NN);
#pragma unroll
        for (int k = 0; k < 2; ++k) {
            const int m = lane + (k << 6);
            half8 c8 = Crow[m];
            float4 va = V4[2 * m];
            float4 vb = V4[2 * m + 1];
            float vv[8] = {va.x, va.y, va.z, va.w, vb.x, vb.y, vb.z, vb.w};
#pragma unroll
            for (int j = 0; j < 8; ++j) {
                float c = (float)c8[j];
                csum += EXP2F((ui + vv[j] - c) * K2) * c;
            }
        }
    }
#pragma unroll
    for (int off = 32; off > 0; off >>= 1) csum += __shfl_xor(csum, off);
    if (lane == 0) red[wave] = csum;
    __syncthreads();
    if (tid == 0)
        atomicAdd(out, (red[0] + red[1] + red[2] + red[3]) * (1.0f / 16.0f));
}

extern "C" void kernel_launch(void* const* d_in, const int* in_sizes, int n_in,
                              void* d_out, int out_size, void* d_ws, size_t ws_size,
                              hipStream_t stream) {
    const float* x = (const float*)d_in[0];  // output: [16,1024,32] fp32
    const float* y = (const float*)d_in[1];  // labels: [16,1024,32] fp32

    char* wsb = (char*)d_ws;
    _Float16* C  = (_Float16*)wsb;                   // 32 MB
    _Float16* CT = (_Float16*)(wsb + 33554432);      // 32 MB

    // padded control region (all zeroed each call)
    float* u       = (float*)(wsb + 67108864);       // 16384 f
    float* v       = u + 16384;                      // 16384 f
    float* errB    = v + 16384;                      // 100*16 lines x 16 f = 25600
    float* gerr    = errB + 25600;                   // 100 x 64 f = 6400
    int*   gdone   = (int*)(gerr + 6400);            // 100 x 64 i = 6400
    int*   barcnt  = gdone + 6400;                   // 16 x 64 i = 1024
    int*   bargen  = barcnt + 1024;                  // 16 x 64 i = 1024
    int*   flagrep = bargen + 1024;                  // 100*8 x 64 i = 51200
    float* out     = (float*)d_out;

    const size_t ctrl_words = 2 * 16384 + 25600 + 6400 + 6400 + 1024 + 1024 + 51200;
    (void)hipMemsetAsync(u, 0, ctrl_words * 4, stream);
    (void)hipMemsetAsync(out, 0, sizeof(float), stream);

    build_dist<<<dim3(16 * 64), dim3(256), 0, stream>>>(x, y, C);
    build_dist<<<dim3(16 * 64), dim3(256), 0, stream>>>(y, x, CT);

    // one persistent launch replaces 200 lse_pass dispatches
    sinkhorn_persist<<<dim3(1024), dim3(256), 0, stream>>>(
        C, CT, u, v, errB, gerr, gdone, barcnt, bargen, flagrep);

    cost_kernel<<<dim3(512), dim3(256), 0, stream>>>(C, u, v, out);
}

// Round 6
// 2059.698 us; speedup vs baseline: 5.5687x; 3.1513x over previous
//
#include <hip/hip_runtime.h>

// Problem constants (B=16, N=M=1024, D=32)
constexpr int   NN       = 1024;
constexpr float EPSf     = 1e-3f;
constexpr int   MAX_ITER = 100;

// exp2-domain scale: arg = (v - C) * (1/eps) * log2(e)
#define K2      1442.6950408889634f
#define TWOK2   2885.3900817779268f
#define LN2f    0.6931471805599453f
#define LOGK    (-6.9314616f)   // log(1/1024 + 1e-8)

#define EXP2F(x) __builtin_amdgcn_exp2f(x)   // 2^x
#define LOG2F(x) __builtin_amdgcn_logf(x)    // log2(x)

typedef _Float16 f16x8 __attribute__((ext_vector_type(8)));
typedef float    f32x4 __attribute__((ext_vector_type(4)));

// (m,s) streaming-LSE merge: (ma,sa) <- (ma,sa) (+) (mb,sb)
__device__ __forceinline__ void msmerge(float& ma, float& sa, float mb, float sb)
{
    const float m2 = fmaxf(ma, mb);
    sa = fmaf(sa, EXP2F(ma - m2), sb * EXP2F(mb - m2));
    ma = m2;
}

// ---------------------------------------------------------------------------
// prep: X,Y fp32 -> fp16 copies + fp32 row sum-of-squares. One thread per row.
// C is NEVER materialized: every consumer computes C = xsq_i + ysq_j - 2<x,y>
// with the same fp16 operands + MFMA, so C is consistent across all kernels.
// ---------------------------------------------------------------------------
__global__ __launch_bounds__(256) void prep(
    const float* __restrict__ X, const float* __restrict__ Y,
    _Float16* __restrict__ Xh, _Float16* __restrict__ Yh,
    float* __restrict__ xsq, float* __restrict__ ysq)
{
    const int gid = blockIdx.x * 256 + threadIdx.x;   // 0..32767
    const float* src; _Float16* dst; float* sq; int row;
    if (gid < 16384) { src = X; dst = Xh; sq = xsq; row = gid; }
    else             { src = Y; dst = Yh; sq = ysq; row = gid - 16384; }

    const float4* s4 = (const float4*)(src + (size_t)row * 32);
    float acc = 0.f;
#pragma unroll
    for (int i = 0; i < 4; ++i) {
        float4 a = s4[2 * i], b = s4[2 * i + 1];
        acc += a.x*a.x + a.y*a.y + a.z*a.z + a.w*a.w;
        acc += b.x*b.x + b.y*b.y + b.z*b.z + b.w*b.w;
        f16x8 h = {(_Float16)a.x, (_Float16)a.y, (_Float16)a.z, (_Float16)a.w,
                   (_Float16)b.x, (_Float16)b.y, (_Float16)b.z, (_Float16)b.w};
        *(f16x8*)(dst + (size_t)row * 32 + i * 8) = h;
    }
    sq[row] = acc;
}

// ---------------------------------------------------------------------------
// One Sinkhorn half-step via MFMA: vout_i = eps*(LOGK - lse_j((vin_j - C_ij)/eps))
// with C_ij = asq_i + bsq_j - 2*dot(Ah_i, Bh_j) computed on the fly
// (mfma_f32_16x16x32_f16: one instruction per 16x16 tile, K=32 = D exactly).
//
// Grid 256 x 1024: block (b = blk&15, blk>>4 of 16) owns 64 rows x 1024 cols
// of one batch. b = blockIdx&15 pins all 16 blocks of a batch to one XCD
// (blockIdx%8 round-robin -> stride-16 blocks share an XCD) so Bh[b] stays
// L2-hot. 16 waves = 4 row-stripes x 4 col-chunks; each wave: 16 MFMA tiles.
// LSE is branch-free online max-shift (safe for any magnitudes, incl. it=0).
// D-frag layout (verified, dtype-indep): col=lane&15, row=(lane>>4)*4+reg.
// A-frag: row=lane&15, k=(lane>>4)*8+j. B-frag: col=lane&15, k=(lane>>4)*8+j.
// ---------------------------------------------------------------------------
__global__ __launch_bounds__(1024, 1) void lse_mfma_pass(
    const _Float16* __restrict__ Ah,   // row-side fp16 [16][1024][32]
    const _Float16* __restrict__ Bh,   // col-side fp16
    const float* __restrict__ asq,     // |a_i|^2
    const float* __restrict__ bsq,     // |b_j|^2
    const float* __restrict__ vin,     // v (u-pass) / u (v-pass)
    float* __restrict__ vout,          // u (u-pass) / v (v-pass)
    float* __restrict__ err,           // err[16][128]
    int* __restrict__ dflag, int it, int do_err)
{
    __shared__ _Float16 Yl[32768];     // 64 KB staged Bh[b]; aliased after use
    float* mrg = (float*)Yl;           // [64 rows][4 waves][2] after consumption

    const int tid = threadIdx.x;
    const int b   = blockIdx.x & 15, blk = blockIdx.x >> 4;

    // freeze chain (v-pass only; err[.][it] complete from this it's u-pass)
    if (!do_err && blockIdx.x == 0 && tid < 16) {
        float e = err[(tid << 7) + it];
        e += __shfl_xor(e, 1); e += __shfl_xor(e, 2);
        e += __shfl_xor(e, 4); e += __shfl_xor(e, 8);
        if (tid == 0) dflag[it + 1] = dflag[it] | (e < 1.6f ? 1 : 0);
    }
    if (dflag[it]) return;   // frozen: u,v keep their converged values

    {   // stage Bh[b] (64 KB) into LDS: 1024 thr x 4 x 16B, coalesced
        const float4* src = (const float4*)(Bh + ((size_t)b << 15));
        float4* dst = (float4*)Yl;
#pragma unroll
        for (int i = 0; i < 4; ++i) dst[tid + (i << 10)] = src[tid + (i << 10)];
    }
    __syncthreads();

    const int wave = tid >> 6, lane = tid & 63;
    const int wr = wave >> 2, wc = wave & 3;
    const int l15 = lane & 15, l4 = lane >> 4;
    const int rowb = (blk << 6) + (wr << 4);            // wave's 16-row stripe

    // A fragment: rows rowb+l15, k = l4*8..+7 (wave covers 1 KB contiguously)
    const f16x8 afrag = *(const f16x8*)(Ah + ((size_t)b << 15) +
                                        ((size_t)(rowb + l15) << 5) + (l4 << 3));
    // asq*K2 for this lane's 4 D rows: rows rowb + l4*4 + r
    const float4 xs4 = *(const float4*)(asq + (b << 10) + rowb + (l4 << 2));
    const float xk[4] = {xs4.x * K2, xs4.y * K2, xs4.z * K2, xs4.w * K2};

    // per-col terms for this lane's 16 tile-columns: w = (vin - bsq)*K2
    float wreg[16];
#pragma unroll
    for (int t = 0; t < 16; ++t) {
        const int c = (b << 10) + (wc << 8) + (t << 4) + l15;
        wreg[t] = (vin[c] - bsq[c]) * K2;
    }

    float m[4] = {-3.4e38f, -3.4e38f, -3.4e38f, -3.4e38f};
    float s[4] = {0.f, 0.f, 0.f, 0.f};

#pragma unroll 4
    for (int t = 0; t < 16; ++t) {
        const int col = (wc << 8) + (t << 4) + l15;
        const f16x8 bfrag = *(const f16x8*)(Yl + ((size_t)col << 5) + (l4 << 3));
        f32x4 z = {0.f, 0.f, 0.f, 0.f};
        f32x4 d = __builtin_amdgcn_mfma_f32_16x16x32_f16(afrag, bfrag, z, 0, 0, 0);
#pragma unroll
        for (int r = 0; r < 4; ++r) {
            // arg = (vin_j - asq_i - bsq_j + 2*dot) * K2, exp2 domain
            const float arg = fmaf(d[r], TWOK2, wreg[t] - xk[r]);
            const float big = fmaxf(m[r], arg);
            const float sml = fminf(m[r], arg);
            const float e   = EXP2F(sml - big);
            s[r] = (arg > m[r]) ? fmaf(s[r], e, 1.0f) : (s[r] + e);
            m[r] = big;
        }
    }

    // intra-wave merge across the 16 column-owners (lanes sharing l4)
#pragma unroll
    for (int off = 1; off < 16; off <<= 1)
#pragma unroll
        for (int r = 0; r < 4; ++r)
            msmerge(m[r], s[r], __shfl_xor(m[r], off), __shfl_xor(s[r], off));

    __syncthreads();   // Yl fully consumed -> safe to alias as mrg

    if (l15 == 0) {
#pragma unroll
        for (int r = 0; r < 4; ++r) {
            const int rb = (wr << 4) + (l4 << 2) + r;     // row within block
            mrg[(rb << 3) + (wc << 1)]     = m[r];
            mrg[(rb << 3) + (wc << 1) + 1] = s[r];
        }
    }
    __syncthreads();

    if (tid < 64) {   // wave 0: one thread per row -> final merge + update
        float M = mrg[(tid << 3)],     S = mrg[(tid << 3) + 1];
        msmerge(M, S, mrg[(tid << 3) + 2], mrg[(tid << 3) + 3]);
        msmerge(M, S, mrg[(tid << 3) + 4], mrg[(tid << 3) + 5]);
        msmerge(M, S, mrg[(tid << 3) + 6], mrg[(tid << 3) + 7]);
        const float lse2 = M + LOG2F(S);
        const float nv = EPSf * (LOGK - lse2 * LN2f);
        const int gr = (b << 10) + (blk << 6) + tid;
        float werr = 0.f;
        if (do_err) werr = fabsf(nv - vout[gr]);
        vout[gr] = nv;
#pragma unroll
        for (int off = 32; off > 0; off >>= 1) werr += __shfl_xor(werr, off);
        if (do_err && tid == 0) atomicAdd(err + (b << 7) + it, werr);
    }
}

// ---------------------------------------------------------------------------
// cost = mean_b sum_ij exp((u_i + v_j - C_ij)/eps) * C_ij, with C computed by
// the SAME fp16+MFMA path as the iteration (consistency is mandatory: the
// (u,v) fixed point must see the same C here, else exp(dC/eps) explodes).
// Same geometry as lse_mfma_pass.
// ---------------------------------------------------------------------------
__global__ __launch_bounds__(1024, 1) void cost_mfma(
    const _Float16* __restrict__ Xh, const _Float16* __restrict__ Yh,
    const float* __restrict__ xsq, const float* __restrict__ ysq,
    const float* __restrict__ u, const float* __restrict__ v,
    float* __restrict__ out)
{
    __shared__ _Float16 Yl[32768];
    float* red = (float*)Yl;   // aliased after use
    const int tid = threadIdx.x;
    const int b   = blockIdx.x & 15, blk = blockIdx.x >> 4;

    {   const float4* src = (const float4*)(Yh + ((size_t)b << 15));
        float4* dst = (float4*)Yl;
#pragma unroll
        for (int i = 0; i < 4; ++i) dst[tid + (i << 10)] = src[tid + (i << 10)];
    }
    __syncthreads();

    const int wave = tid >> 6, lane = tid & 63;
    const int wr = wave >> 2, wc = wave & 3;
    const int l15 = lane & 15, l4 = lane >> 4;
    const int rowb = (blk << 6) + (wr << 4);

    const f16x8 afrag = *(const f16x8*)(Xh + ((size_t)b << 15) +
                                        ((size_t)(rowb + l15) << 5) + (l4 << 3));
    const float4 xs4 = *(const float4*)(xsq + (b << 10) + rowb + (l4 << 2));
    const float xs[4] = {xs4.x, xs4.y, xs4.z, xs4.w};
    const float4 uu4 = *(const float4*)(u + (b << 10) + rowb + (l4 << 2));
    const float uk[4] = {uu4.x * K2, uu4.y * K2, uu4.z * K2, uu4.w * K2};

    float vk[16], ys[16];
#pragma unroll
    for (int t = 0; t < 16; ++t) {
        const int c = (b << 10) + (wc << 8) + (t << 4) + l15;
        vk[t] = v[c] * K2;
        ys[t] = ysq[c];
    }

    float csum = 0.f;
#pragma unroll 4
    for (int t = 0; t < 16; ++t) {
        const int col = (wc << 8) + (t << 4) + l15;
        const f16x8 bfrag = *(const f16x8*)(Yl + ((size_t)col << 5) + (l4 << 3));
        f32x4 z = {0.f, 0.f, 0.f, 0.f};
        f32x4 d = __builtin_amdgcn_mfma_f32_16x16x32_f16(afrag, bfrag, z, 0, 0, 0);
#pragma unroll
        for (int r = 0; r < 4; ++r) {
            const float C   = fmaf(-2.f, d[r], xs[r] + ys[t]);
            const float arg = fmaf(C, -K2, uk[r] + vk[t]);
            csum += EXP2F(arg) * C;
        }
    }
#pragma unroll
    for (int off = 32; off > 0; off >>= 1) csum += __shfl_xor(csum, off);

    __syncthreads();   // Yl consumed -> alias as red
    if (lane == 0) red[wave] = csum;
    __syncthreads();
    if (tid == 0) {
        float tot = 0.f;
#pragma unroll
        for (int w = 0; w < 16; ++w) tot += red[w];
        atomicAdd(out, tot * (1.0f / 16.0f));
    }
}

extern "C" void kernel_launch(void* const* d_in, const int* in_sizes, int n_in,
                              void* d_out, int out_size, void* d_ws, size_t ws_size,
                              hipStream_t stream) {
    const float* x = (const float*)d_in[0];  // output: [16,1024,32] fp32
    const float* y = (const float*)d_in[1];  // labels: [16,1024,32] fp32

    char* wsb = (char*)d_ws;
    _Float16* Xh = (_Float16*)wsb;                     // 1 MB  [16][1024][32]
    _Float16* Yh = (_Float16*)(wsb + (1u << 20));      // 1 MB
    float* xsq   = (float*)(wsb + (2u << 20));         // 16384 f
    float* ysq   = xsq + 16384;                        // 16384 f
    float* u     = ysq + 16384;                        // 16384 f
    float* v     = u + 16384;                          // 16384 f
    float* err   = v + 16384;                          // [16][128]
    int*   dflag = (int*)(err + 2048);                 // 128
    float* out   = (float*)d_out;

    // u, v, err, dflag contiguous — zero them (+ out) every call
    (void)hipMemsetAsync(u, 0, (size_t)(2 * 16384 + 2048 + 128) * 4, stream);
    (void)hipMemsetAsync(out, 0, sizeof(float), stream);

    prep<<<dim3(128), dim3(256), 0, stream>>>(x, y, Xh, Yh, xsq, ysq);

    for (int it = 0; it < MAX_ITER; ++it) {
        // u-pass: rows = x, cols = y
        lse_mfma_pass<<<dim3(256), dim3(1024), 0, stream>>>(
            Xh, Yh, xsq, ysq, v, u, err, dflag, it, 1);
        // v-pass: rows = y, cols = x
        lse_mfma_pass<<<dim3(256), dim3(1024), 0, stream>>>(
            Yh, Xh, ysq, xsq, u, v, err, dflag, it, 0);
    }

    cost_mfma<<<dim3(256), dim3(1024), 0, stream>>>(Xh, Yh, xsq, ysq, u, v, out);
}

// Round 7
// 1366.251 us; speedup vs baseline: 8.3951x; 1.5076x over previous
//
#include <hip/hip_runtime.h>

// Problem constants (B=16, N=M=1024, D=32)
constexpr int   NN       = 1024;
constexpr float EPSf     = 1e-3f;
constexpr int   MAX_ITER = 100;

// exp2-domain scale: arg = (v - C) * (1/eps) * log2(e)
#define K2      1442.6950408889634f
#define TWOK2   2885.3900817779268f
#define LN2f    0.6931471805599453f
#define INV_LN2 1.4426950408889634f
#define INV_EPS 1000.0f
#define LOGK    (-6.9314616f)   // log(1/1024 + 1e-8)

#define EXP2F(x) __builtin_amdgcn_exp2f(x)   // 2^x
#define LOG2F(x) __builtin_amdgcn_logf(x)    // log2(x)

typedef _Float16 f16x8 __attribute__((ext_vector_type(8)));
typedef float    f32x4 __attribute__((ext_vector_type(4)));

// (m,s) streaming-LSE merge: (ma,sa) <- (ma,sa) (+) (mb,sb)
__device__ __forceinline__ void msmerge(float& ma, float& sa, float mb, float sb)
{
    const float m2 = fmaxf(ma, mb);
    sa = fmaf(sa, EXP2F(ma - m2), sb * EXP2F(mb - m2));
    ma = m2;
}

// ---------------------------------------------------------------------------
// prep: X,Y fp32 -> fp16 copies + fp32 row sum-of-squares. One thread per row.
// C is NEVER materialized: every consumer computes C = xsq_i + ysq_j - 2<x,y>
// with the same fp16 operands + MFMA, so C is consistent across all kernels.
// ---------------------------------------------------------------------------
__global__ __launch_bounds__(256) void prep(
    const float* __restrict__ X, const float* __restrict__ Y,
    _Float16* __restrict__ Xh, _Float16* __restrict__ Yh,
    float* __restrict__ xsq, float* __restrict__ ysq)
{
    const int gid = blockIdx.x * 256 + threadIdx.x;   // 0..32767
    const float* src; _Float16* dst; float* sq; int row;
    if (gid < 16384) { src = X; dst = Xh; sq = xsq; row = gid; }
    else             { src = Y; dst = Yh; sq = ysq; row = gid - 16384; }

    const float4* s4 = (const float4*)(src + (size_t)row * 32);
    float acc = 0.f;
#pragma unroll
    for (int i = 0; i < 4; ++i) {
        float4 a = s4[2 * i], b = s4[2 * i + 1];
        acc += a.x*a.x + a.y*a.y + a.z*a.z + a.w*a.w;
        acc += b.x*b.x + b.y*b.y + b.z*b.z + b.w*b.w;
        f16x8 h = {(_Float16)a.x, (_Float16)a.y, (_Float16)a.z, (_Float16)a.w,
                   (_Float16)b.x, (_Float16)b.y, (_Float16)b.z, (_Float16)b.w};
        *(f16x8*)(dst + (size_t)row * 32 + i * 8) = h;
    }
    sq[row] = acc;
}

// XOR-swizzled LDS slot for row/col c, 16B-chunk k: kills the 4x bank
// serialization of the linear layout (quarter-wave banks were {0,16}+4k).
// Enumeration: read quarter (fixed l4, c=base..base+15) hits all 32 banks
// exactly twice (ideal for b128); staging writes likewise 8/bank.
#define YSLOT(c, k) (((c) << 5) + (((k) ^ (((c) >> 1) & 3)) << 3))   // f16 units

// ---------------------------------------------------------------------------
// One Sinkhorn half-step via MFMA, C on the fly (C = asq_i + bsq_j - 2<a,b>).
// Grid 256 x 1024: block (b = blk&15) owns 64 rows x 1024 cols of batch b
// (b&7 pins a batch's 16 blocks to one XCD -> Bh[b] L2-hot).
// FAST PATH (baseline-proven): shift args by M0 derived from the PREVIOUS
// iterate (no max pass, plain sums); block-uniform FALLBACK to online
// max-shifted LSE when any row's sum leaves (1e-27, 1e38) — fires at it=0.
// Frag layouts (verified): D col=lane&15,row=(lane>>4)*4+reg; A row=lane&15,
// k=(lane>>4)*8+j; B col=lane&15, k=(lane>>4)*8+j.
// ---------------------------------------------------------------------------
__global__ __launch_bounds__(1024, 1) void lse_mfma_pass(
    const _Float16* __restrict__ Ah,   // row-side fp16 [16][1024][32]
    const _Float16* __restrict__ Bh,   // col-side fp16
    const float* __restrict__ asq,     // |a_i|^2
    const float* __restrict__ bsq,     // |b_j|^2
    const float* __restrict__ vin,     // v (u-pass) / u (v-pass)
    float* __restrict__ vout,          // u (u-pass) / v (v-pass)
    float* __restrict__ err,           // err[16][128]
    int* __restrict__ dflag, int it, int do_err)
{
    __shared__ _Float16 Yl[32768];     // 64 KB B-tile, swizzled rows
    __shared__ float    wk[1024];      // (vin - bsq) * K2 per column
    __shared__ float    mrg[64][8];    // per-row per-wc partials
    __shared__ int      s_fb;

    const int tid = threadIdx.x;
    const int b   = blockIdx.x & 15, blk = blockIdx.x >> 4;

    // freeze chain (v-pass only; err[.][it] complete from this it's u-pass)
    if (!do_err && blockIdx.x == 0 && tid < 16) {
        float e = err[(tid << 7) + it];
        e += __shfl_xor(e, 1); e += __shfl_xor(e, 2);
        e += __shfl_xor(e, 4); e += __shfl_xor(e, 8);
        if (tid == 0) dflag[it + 1] = dflag[it] | (e < 1.6f ? 1 : 0);
    }
    if (dflag[it]) return;   // frozen: u,v keep their converged values
    if (tid == 0) s_fb = 0;

    {   // stage Bh[b] (64 KB) swizzled + wk (4 KB)
        const float4* src = (const float4*)(Bh + ((size_t)b << 15));
#pragma unroll
        for (int i = 0; i < 4; ++i) {
            const int g = tid + (i << 10);
            const int row = g >> 2, k = g & 3;
            *(float4*)(Yl + YSLOT(row, k)) = src[g];
        }
        const int c = (b << 10) + tid;
        wk[tid] = (vin[c] - bsq[c]) * K2;
    }
    __syncthreads();

    const int wave = tid >> 6, lane = tid & 63;
    const int wr = wave >> 2, wc = wave & 3;
    const int l15 = lane & 15, l4 = lane >> 4;
    const int rowb = (blk << 6) + (wr << 4);            // wave's 16-row stripe

    // A fragment: rows rowb+l15, k = l4*8..+7 (wave covers 1 KB contiguously)
    const f16x8 afrag = *(const f16x8*)(Ah + ((size_t)b << 15) +
                                        ((size_t)(rowb + l15) << 5) + (l4 << 3));
    // per-D-row terms: rows rowb + l4*4 + r
    const float4 xs4 = *(const float4*)(asq + (b << 10) + rowb + (l4 << 2));
    const float4 uo4 = *(const float4*)(vout + (b << 10) + rowb + (l4 << 2));
    const float xk[4] = {xs4.x * K2, xs4.y * K2, xs4.z * K2, xs4.w * K2};
    // xm = asq*K2 + M0,  M0 = (LOGK - uo/eps)/ln2  (prev-iterate shift)
    float xm[4];
    {
        const float u4[4] = {uo4.x, uo4.y, uo4.z, uo4.w};
#pragma unroll
        for (int r = 0; r < 4; ++r)
            xm[r] = xk[r] + (LOGK - u4[r] * INV_EPS) * INV_LN2;
    }

    // per-col terms for this lane's 16 tile-columns
    float wreg[16];
#pragma unroll
    for (int t = 0; t < 16; ++t) wreg[t] = wk[(wc << 8) + (t << 4) + l15];

    // ---------------- FAST PATH: plain sums shifted by M0 ----------------
    float s[4] = {0.f, 0.f, 0.f, 0.f};
#pragma unroll 4
    for (int t = 0; t < 16; ++t) {
        const int col = (wc << 8) + (t << 4) + l15;
        const f16x8 bfrag = *(const f16x8*)(Yl + YSLOT(col, l4));
        f32x4 z = {0.f, 0.f, 0.f, 0.f};
        f32x4 d = __builtin_amdgcn_mfma_f32_16x16x32_f16(afrag, bfrag, z, 0, 0, 0);
#pragma unroll
        for (int r = 0; r < 4; ++r)
            s[r] += EXP2F(fmaf(d[r], TWOK2, wreg[t] - xm[r]));
    }
#pragma unroll
    for (int off = 1; off < 16; off <<= 1)
#pragma unroll
        for (int r = 0; r < 4; ++r) s[r] += __shfl_xor(s[r], off);
    if (l15 == 0) {
#pragma unroll
        for (int r = 0; r < 4; ++r) mrg[(wr << 4) + (l4 << 2) + r][wc] = s[r];
    }
    __syncthreads();

    // range check (wave 0) -> block-uniform fallback decision
    float S = 0.f, uo = 0.f, M0r = 0.f;
    int gr = 0;
    if (tid < 64) {
        S = mrg[tid][0] + mrg[tid][1] + mrg[tid][2] + mrg[tid][3];
        gr = (b << 10) + (blk << 6) + tid;
        uo = vout[gr];
        M0r = (LOGK - uo * INV_EPS) * INV_LN2;
        if (!(S >= 1e-27f && S <= 1e38f)) s_fb = 1;
    }
    __syncthreads();

    if (!s_fb) {
        if (tid < 64) {
            const float lse2 = M0r + LOG2F(S);
            const float nv = EPSf * (LOGK - lse2 * LN2f);
            float werr = do_err ? fabsf(nv - uo) : 0.f;
            vout[gr] = nv;
#pragma unroll
            for (int off = 32; off > 0; off >>= 1) werr += __shfl_xor(werr, off);
            if (do_err && tid == 0) atomicAdd(err + (b << 7) + it, werr);
        }
        return;
    }

    // ------------- FALLBACK: online max-shifted LSE (it=0, drift) -------------
    float m[4] = {-3.4e38f, -3.4e38f, -3.4e38f, -3.4e38f};
    float sf[4] = {0.f, 0.f, 0.f, 0.f};
#pragma unroll 4
    for (int t = 0; t < 16; ++t) {
        const int col = (wc << 8) + (t << 4) + l15;
        const f16x8 bfrag = *(const f16x8*)(Yl + YSLOT(col, l4));
        f32x4 z = {0.f, 0.f, 0.f, 0.f};
        f32x4 d = __builtin_amdgcn_mfma_f32_16x16x32_f16(afrag, bfrag, z, 0, 0, 0);
#pragma unroll
        for (int r = 0; r < 4; ++r) {
            const float arg = fmaf(d[r], TWOK2, wreg[t] - xk[r]);
            const float big = fmaxf(m[r], arg);
            const float e   = EXP2F(fminf(m[r], arg) - big);
            sf[r] = (arg > m[r]) ? fmaf(sf[r], e, 1.0f) : (sf[r] + e);
            m[r] = big;
        }
    }
#pragma unroll
    for (int off = 1; off < 16; off <<= 1)
#pragma unroll
        for (int r = 0; r < 4; ++r)
            msmerge(m[r], sf[r], __shfl_xor(m[r], off), __shfl_xor(sf[r], off));
    if (l15 == 0) {
#pragma unroll
        for (int r = 0; r < 4; ++r) {
            const int rb = (wr << 4) + (l4 << 2) + r;
            mrg[rb][wc]     = m[r];
            mrg[rb][4 + wc] = sf[r];
        }
    }
    __syncthreads();

    if (tid < 64) {
        float M = mrg[tid][0], Sf = mrg[tid][4];
        msmerge(M, Sf, mrg[tid][1], mrg[tid][5]);
        msmerge(M, Sf, mrg[tid][2], mrg[tid][6]);
        msmerge(M, Sf, mrg[tid][3], mrg[tid][7]);
        const float lse2 = M + LOG2F(Sf);
        const float nv = EPSf * (LOGK - lse2 * LN2f);
        float werr = do_err ? fabsf(nv - uo) : 0.f;
        vout[gr] = nv;
#pragma unroll
        for (int off = 32; off > 0; off >>= 1) werr += __shfl_xor(werr, off);
        if (do_err && tid == 0) atomicAdd(err + (b << 7) + it, werr);
    }
}

// ---------------------------------------------------------------------------
// cost = mean_b sum_ij exp((u_i + v_j - C_ij)/eps) * C_ij, C via the SAME
// fp16+MFMA path (consistency with the (u,v) fixed point is mandatory).
// Same geometry + swizzle as lse_mfma_pass.
// ---------------------------------------------------------------------------
__global__ __launch_bounds__(1024, 1) void cost_mfma(
    const _Float16* __restrict__ Xh, const _Float16* __restrict__ Yh,
    const float* __restrict__ xsq, const float* __restrict__ ysq,
    const float* __restrict__ u, const float* __restrict__ v,
    float* __restrict__ out)
{
    __shared__ _Float16 Yl[32768];
    __shared__ float red[16];
    const int tid = threadIdx.x;
    const int b   = blockIdx.x & 15, blk = blockIdx.x >> 4;

    {   const float4* src = (const float4*)(Yh + ((size_t)b << 15));
#pragma unroll
        for (int i = 0; i < 4; ++i) {
            const int g = tid + (i << 10);
            const int row = g >> 2, k = g & 3;
            *(float4*)(Yl + YSLOT(row, k)) = src[g];
        }
    }
    __syncthreads();

    const int wave = tid >> 6, lane = tid & 63;
    const int wr = wave >> 2, wc = wave & 3;
    const int l15 = lane & 15, l4 = lane >> 4;
    const int rowb = (blk << 6) + (wr << 4);

    const f16x8 afrag = *(const f16x8*)(Xh + ((size_t)b << 15) +
                                        ((size_t)(rowb + l15) << 5) + (l4 << 3));
    const float4 xs4 = *(const float4*)(xsq + (b << 10) + rowb + (l4 << 2));
    const float xs[4] = {xs4.x, xs4.y, xs4.z, xs4.w};
    const float4 uu4 = *(const float4*)(u + (b << 10) + rowb + (l4 << 2));
    const float uk[4] = {uu4.x * K2, uu4.y * K2, uu4.z * K2, uu4.w * K2};

    float vk[16], ys[16];
#pragma unroll
    for (int t = 0; t < 16; ++t) {
        const int c = (b << 10) + (wc << 8) + (t << 4) + l15;
        vk[t] = v[c] * K2;
        ys[t] = ysq[c];
    }

    float csum = 0.f;
#pragma unroll 4
    for (int t = 0; t < 16; ++t) {
        const int col = (wc << 8) + (t << 4) + l15;
        const f16x8 bfrag = *(const f16x8*)(Yl + YSLOT(col, l4));
        f32x4 z = {0.f, 0.f, 0.f, 0.f};
        f32x4 d = __builtin_amdgcn_mfma_f32_16x16x32_f16(afrag, bfrag, z, 0, 0, 0);
#pragma unroll
        for (int r = 0; r < 4; ++r) {
            const float C   = fmaf(-2.f, d[r], xs[r] + ys[t]);
            const float arg = fmaf(C, -K2, uk[r] + vk[t]);
            csum += EXP2F(arg) * C;
        }
    }
#pragma unroll
    for (int off = 32; off > 0; off >>= 1) csum += __shfl_xor(csum, off);

    if (lane == 0) red[wave] = csum;
    __syncthreads();
    if (tid == 0) {
        float tot = 0.f;
#pragma unroll
        for (int w = 0; w < 16; ++w) tot += red[w];
        atomicAdd(out, tot * (1.0f / 16.0f));
    }
}

extern "C" void kernel_launch(void* const* d_in, const int* in_sizes, int n_in,
                              void* d_out, int out_size, void* d_ws, size_t ws_size,
                              hipStream_t stream) {
    const float* x = (const float*)d_in[0];  // output: [16,1024,32] fp32
    const float* y = (const float*)d_in[1];  // labels: [16,1024,32] fp32

    char* wsb = (char*)d_ws;
    _Float16* Xh = (_Float16*)wsb;                     // 1 MB  [16][1024][32]
    _Float16* Yh = (_Float16*)(wsb + (1u << 20));      // 1 MB
    float* xsq   = (float*)(wsb + (2u << 20));         // 16384 f
    float* ysq   = xsq + 16384;                        // 16384 f
    float* u     = ysq + 16384;                        // 16384 f
    float* v     = u + 16384;                          // 16384 f
    float* err   = v + 16384;                          // [16][128]
    int*   dflag = (int*)(err + 2048);                 // 128
    float* out   = (float*)d_out;

    // u, v, err, dflag contiguous — zero them (+ out) every call
    (void)hipMemsetAsync(u, 0, (size_t)(2 * 16384 + 2048 + 128) * 4, stream);
    (void)hipMemsetAsync(out, 0, sizeof(float), stream);

    prep<<<dim3(128), dim3(256), 0, stream>>>(x, y, Xh, Yh, xsq, ysq);

    for (int it = 0; it < MAX_ITER; ++it) {
        // u-pass: rows = x, cols = y
        lse_mfma_pass<<<dim3(256), dim3(1024), 0, stream>>>(
            Xh, Yh, xsq, ysq, v, u, err, dflag, it, 1);
        // v-pass: rows = y, cols = x
        lse_mfma_pass<<<dim3(256), dim3(1024), 0, stream>>>(
            Yh, Xh, ysq, xsq, u, v, err, dflag, it, 0);
    }

    cost_mfma<<<dim3(256), dim3(1024), 0, stream>>>(Xh, Yh, xsq, ysq, u, v, out);
}